// Round 5
// baseline (11280.019 us; speedup 1.0000x reference)
//
#include <hip/hip_runtime.h>

#define HID    51
#define G4     204    // 4*HID
#define EMB    7
#define VOCAB  282
#define TT     1024
#define BB     256

__device__ __forceinline__ float tanh_fast(float x) {
    return 1.0f - 2.0f / (__expf(2.0f * x) + 1.0f);
}

// LDS-only barrier: wait ds ops, DO NOT drain vmcnt (global loads are ordered by
// register deps; stores need no intra-loop visibility). Keeps eproj prefetch and
// output stores in flight across steps.
#define BAR() asm volatile("s_waitcnt lgkmcnt(0)\n\ts_barrier" ::: "memory")

// quad-lane activation + gate gather + cell update (lanes q=0..3 hold i,f,g,o)
__device__ __forceinline__ float lstm_act(float x, int q, float& c) {
    const float As = (q == 2) ? 2.f : 1.f;
    const float Bs = (q == 2) ? -1.f : 0.f;
    const float act = As / (1.f + __expf(-As * x)) + Bs;  // sigmoid or tanh
    const float v1 = __shfl_xor(act, 1);
    const float v2 = __shfl_xor(act, 2);
    const float v3 = __shfl_xor(v2, 1);
    const float t0 = (q & 1) ? v1 : act, t1 = (q & 1) ? act : v1;
    const float t2 = (q & 1) ? v3 : v2,  t3 = (q & 1) ? v2 : v3;
    const float I = (q & 2) ? t2 : t0, F = (q & 2) ? t3 : t1;
    const float G = (q & 2) ? t0 : t2, O = (q & 2) ? t1 : t3;
    const float cn = F * c + I * G;
    c = cn;
    return O * tanh_fast(cn);
}

// ---------- Kernel A: eproj[v][j] = b1[j] + sum_e embed[v][e]*w_ih1[j][e] ----------
__global__ void eproj_kernel(const float* __restrict__ embed,
                             const float* __restrict__ w_ih1,
                             const float* __restrict__ b1,
                             float* __restrict__ eproj) {
    int idx = blockIdx.x * blockDim.x + threadIdx.x;
    if (idx >= VOCAB * G4) return;
    int v = idx / G4;
    int j = idx - v * G4;
    float acc = b1[j];
    #pragma unroll
    for (int e = 0; e < EMB; e++)
        acc += embed[v * EMB + e] * w_ih1[j * EMB + e];
    eproj[idx] = acc;
}

// ---------- Kernel B: fused recurrent LSTM + output projection -------------------
// One block per batch item. 12 waves:
//   waves 0-3 (L1):  h1(s)        waves 4-7 (L2): h2(s-1)
//   waves 8-11 (OUT): logits(s-2) -> d_out directly
// One lgkm-only barrier per super-step.
// amdgpu_waves_per_eu(3,3): pin occupancy target to EXACTLY 3 waves/EU -> VGPR
// budget 512/3 ~= 168, so wA[51]+wB[51] live in registers. launch_bounds(768,3)
// only set the MIN of the range; the allocator still targeted 6 waves/EU and
// spilled the arrays to scratch (VGPR=84, 5 GB/dispatch scratch FETCH in R3/R4).
__launch_bounds__(768)
__attribute__((amdgpu_waves_per_eu(3, 3)))
__global__ void lstm_fused_kernel(const int* __restrict__ input,
                                  const float* __restrict__ eproj,
                                  const float* __restrict__ w_hh1,
                                  const float* __restrict__ w_ih2,
                                  const float* __restrict__ w_hh2,
                                  const float* __restrict__ b2,
                                  const float* __restrict__ w_lin,
                                  const float* __restrict__ b_lin,
                                  float* __restrict__ out) {
    __shared__ __align__(16) float h1b[2][52];   // 208B rows -> 13 aligned float4
    __shared__ __align__(16) float h2b[2][52];
    __shared__ int toks[TT];

    const int tid = threadIdx.x;
    const int b   = blockIdx.x;

    for (int i = tid; i < TT; i += 768) toks[i] = input[b * TT + i];
    if (tid < 52) {
        h1b[0][tid] = 0.f; h1b[1][tid] = 0.f;
        h2b[0][tid] = 0.f; h2b[1][tid] = 0.f;
    }

    const int grp = tid >> 8;          // 0=L1, 1=L2, 2=OUT
    const int lt  = tid & 255;
    // LSTM lane mapping (grp 0/1): 4 lanes per hidden elem own gates i,f,g,o
    const int  w  = lt >> 6;
    const int  l  = lt & 63;
    const int  jj = l >> 2;
    const int  q  = l & 3;
    const int  ne = (w < 3) ? 13 : 12;           // 3*13+12 = 51
    const bool al = (jj < ne);
    const int  j  = 13 * w + jj;
    const int  gs = al ? (q * 51 + j) : 0;
    // OUT mapping (grp 2): lane lt owns col lt; lanes 0..25 also own col 256+lt
    const int  col0 = lt;
    const bool has2 = (lt < 26);
    const int  col1 = has2 ? (256 + lt) : 0;

    float wA[51], wB[51];              // shared across groups -> one VGPR budget
    float bx = 0.f, by = 0.f;
    float c = 0.f;
    float ep_cur = 0.f;

    __syncthreads();                   // toks + zeroed h buffers visible

    if (grp == 0) {
        #pragma unroll
        for (int k = 0; k < 51; k++) { wA[k] = w_hh1[gs * 51 + k]; wB[k] = 0.f; }
        ep_cur = eproj[toks[0] * G4 + gs];
    } else if (grp == 1) {
        #pragma unroll
        for (int k = 0; k < 51; k++) { wA[k] = w_ih2[gs * 51 + k]; wB[k] = w_hh2[gs * 51 + k]; }
        bx = b2[gs];
    } else {
        #pragma unroll
        for (int k = 0; k < 51; k++) { wA[k] = w_lin[col0 * 51 + k]; wB[k] = w_lin[col1 * 51 + k]; }
        bx = b_lin[col0]; by = b_lin[col1];
    }

    const size_t obase = (size_t)b * TT;

    for (int s = 0; s <= TT + 1; ++s) {
        if (grp == 0) {
            if (s < TT) {
                const int sn = (s + 1 < TT) ? (s + 1) : 0;
                const float ep_nxt = eproj[toks[sn] * G4 + gs];   // prefetch, stays in flight
                const float4* hp = (const float4*)h1b[(s + 1) & 1];   // h1(s-1)
                float a0 = 0.f, a1 = 0.f, a2 = 0.f, a3 = 0.f;
                #pragma unroll
                for (int i = 0; i < 13; i++) {
                    float4 hv = hp[i];
                    const int k = 4 * i;
                    a0 += wA[k] * hv.x;
                    if (k + 1 < 51) a1 += wA[k + 1] * hv.y;
                    if (k + 2 < 51) a2 += wA[k + 2] * hv.z;
                    if (k + 3 < 51) a3 += wA[k + 3] * hv.w;
                }
                const float x = (a0 + a1) + (a2 + a3) + ep_cur;
                const float hn = lstm_act(x, q, c);
                if (q == 0 && al) h1b[s & 1][j] = hn;
                ep_cur = ep_nxt;
            }
        } else if (grp == 1) {
            if (s >= 1 && s <= TT) {
                const float4* hp1 = (const float4*)h1b[(s - 1) & 1];  // h1(t)
                const float4* hp2 = (const float4*)h2b[s & 1];        // h2(t-1)
                float a0 = 0.f, a1 = 0.f, a2 = 0.f, a3 = 0.f;
                #pragma unroll
                for (int i = 0; i < 13; i++) {
                    float4 ha = hp1[i];
                    float4 hb = hp2[i];
                    const int k = 4 * i;
                    a0 += wA[k] * ha.x;       a2 += wB[k] * hb.x;
                    if (k + 1 < 51) { a1 += wA[k + 1] * ha.y; a3 += wB[k + 1] * hb.y; }
                    if (k + 2 < 51) { a0 += wA[k + 2] * ha.z; a2 += wB[k + 2] * hb.z; }
                    if (k + 3 < 51) { a1 += wA[k + 3] * ha.w; a3 += wB[k + 3] * hb.w; }
                }
                const float x = (a0 + a1) + (a2 + a3) + bx;
                const float hn = lstm_act(x, q, c);
                if (q == 0 && al) h2b[(s - 1) & 1][j] = hn;
            }
        } else {
            if (s >= 2) {
                const int u = s - 2;
                const float4* hp = (const float4*)h2b[s & 1];         // h2(u)
                float a0 = 0.f, a1 = 0.f, b0 = 0.f, b1v = 0.f;
                #pragma unroll
                for (int i = 0; i < 13; i++) {
                    float4 hv = hp[i];
                    const int k = 4 * i;
                    a0 += wA[k] * hv.x;       b0  += wB[k] * hv.x;
                    if (k + 1 < 51) { a1 += wA[k + 1] * hv.y; b1v += wB[k + 1] * hv.y; }
                    if (k + 2 < 51) { a0 += wA[k + 2] * hv.z; b0  += wB[k + 2] * hv.z; }
                    if (k + 3 < 51) { a1 += wA[k + 3] * hv.w; b1v += wB[k + 3] * hv.w; }
                }
                out[(obase + u) * VOCAB + col0] = a0 + a1 + bx;       // coalesced per wave
                if (has2)
                    out[(obase + u) * VOCAB + col1] = b0 + b1v + by;
            }
        }
        BAR();
    }
}

extern "C" void kernel_launch(void* const* d_in, const int* in_sizes, int n_in,
                              void* d_out, int out_size, void* d_ws, size_t ws_size,
                              hipStream_t stream) {
    const int*   input = (const int*)  d_in[0];
    const float* embed = (const float*)d_in[2];
    const float* w_ih1 = (const float*)d_in[3];
    const float* w_hh1 = (const float*)d_in[4];
    const float* b1    = (const float*)d_in[5];
    const float* w_ih2 = (const float*)d_in[6];
    const float* w_hh2 = (const float*)d_in[7];
    const float* b2    = (const float*)d_in[8];
    const float* w_lin = (const float*)d_in[9];
    const float* b_lin = (const float*)d_in[10];
    float* out   = (float*)d_out;
    float* eproj = (float*)d_ws;     // 282*204*4 = 230 KB scratch

    const int n1 = VOCAB * G4;
    eproj_kernel<<<(n1 + 255) / 256, 256, 0, stream>>>(embed, w_ih1, b1, eproj);
    lstm_fused_kernel<<<BB, 768, 0, stream>>>(input, eproj, w_hh1, w_ih2, w_hh2, b2,
                                              w_lin, b_lin, out);
}

// Round 6
// 11000.243 us; speedup vs baseline: 1.0254x; 1.0254x over previous
//
#include <hip/hip_runtime.h>

#define HID    51
#define G4     204    // 4*HID
#define EMB    7
#define VOCAB  282
#define TT     1024
#define BB     256

__device__ __forceinline__ float tanh_fast(float x) {
    return 1.0f - 2.0f / (__expf(2.0f * x) + 1.0f);
}

// LDS-only barrier: wait ds ops, DO NOT drain vmcnt (global loads are ordered by
// register deps; stores need no intra-loop visibility). Keeps eproj prefetch and
// output stores in flight across steps.
#define BAR() asm volatile("s_waitcnt lgkmcnt(0)\n\ts_barrier" ::: "memory")

// quad-lane activation + gate gather + cell update (lanes q=0..3 hold i,f,g,o)
// __shfl_xor masks 1,2 compile to DPP quad_perm -> VALU pipe, not LDS.
__device__ __forceinline__ float lstm_act(float x, int q, float& c) {
    const float As = (q == 2) ? 2.f : 1.f;
    const float Bs = (q == 2) ? -1.f : 0.f;
    const float act = As / (1.f + __expf(-As * x)) + Bs;  // sigmoid or tanh
    const float v1 = __shfl_xor(act, 1);
    const float v2 = __shfl_xor(act, 2);
    const float v3 = __shfl_xor(v2, 1);
    const float t0 = (q & 1) ? v1 : act, t1 = (q & 1) ? act : v1;
    const float t2 = (q & 1) ? v3 : v2,  t3 = (q & 1) ? v2 : v3;
    const float I = (q & 2) ? t2 : t0, F = (q & 2) ? t3 : t1;
    const float G = (q & 2) ? t0 : t2, O = (q & 2) ? t1 : t3;
    const float cn = F * c + I * G;
    c = cn;
    return O * tanh_fast(cn);
}

// ---------- Kernel A: eproj[v][j] = b1[j] + sum_e embed[v][e]*w_ih1[j][e] ----------
__global__ void eproj_kernel(const float* __restrict__ embed,
                             const float* __restrict__ w_ih1,
                             const float* __restrict__ b1,
                             float* __restrict__ eproj) {
    int idx = blockIdx.x * blockDim.x + threadIdx.x;
    if (idx >= VOCAB * G4) return;
    int v = idx / G4;
    int j = idx - v * G4;
    float acc = b1[j];
    #pragma unroll
    for (int e = 0; e < EMB; e++)
        acc += embed[v * EMB + e] * w_ih1[j * EMB + e];
    eproj[idx] = acc;
}

// ---------- Kernel B: fused recurrent LSTM + output projection -------------------
// One block per batch item. 12 waves:
//   waves 0-3 (L1):  h1(s)        waves 4-7 (L2): h2(s-1)
//   waves 8-11 (OUT): logits(s-2) -> d_out directly
// One lgkm-only barrier per super-step.
//
// REGISTER-BUDGET FIX (R3-R5 all spilled, VGPR=84, 4-5 GB/dispatch scratch HBM):
// with tiny LDS, TWO 12-wave blocks fit per CU, so the backend's occupancy
// heuristic targets 6 waves/EU -> unified VGPR budget 512/6=84 -> wA/wB spill.
// Neither __launch_bounds__(768,3) nor amdgpu_waves_per_eu(3,3) overrode it.
// Fix: make static LDS > 80 KB (toks inflated to 96 KB, genuinely used) so only
// ONE block can reside per CU -> heuristic target 12 waves/CU = 3 waves/EU ->
// budget ~168 VGPR >= ~137 live -> no spill. Grid is 1 block/CU anyway.
#define TOKS_PAD 24576   // 96 KB of int

__launch_bounds__(768, 3)
__global__ void lstm_fused_kernel(const int* __restrict__ input,
                                  const float* __restrict__ eproj,
                                  const float* __restrict__ w_hh1,
                                  const float* __restrict__ w_ih2,
                                  const float* __restrict__ w_hh2,
                                  const float* __restrict__ b2,
                                  const float* __restrict__ w_lin,
                                  const float* __restrict__ b_lin,
                                  float* __restrict__ out) {
    __shared__ __align__(16) float h1b[2][52];   // 208B rows -> 13 aligned float4
    __shared__ __align__(16) float h2b[2][52];
    __shared__ int toks[TOKS_PAD];               // only [0..TT) used; size = occupancy hint

    const int tid = threadIdx.x;
    const int b   = blockIdx.x;

    for (int i = tid; i < TT; i += 768) toks[i] = input[b * TT + i];
    if (tid < 52) {
        h1b[0][tid] = 0.f; h1b[1][tid] = 0.f;
        h2b[0][tid] = 0.f; h2b[1][tid] = 0.f;
    }

    const int grp = tid >> 8;          // 0=L1, 1=L2, 2=OUT
    const int lt  = tid & 255;
    // LSTM lane mapping (grp 0/1): 4 lanes per hidden elem own gates i,f,g,o
    const int  w  = lt >> 6;
    const int  l  = lt & 63;
    const int  jj = l >> 2;
    const int  q  = l & 3;
    const int  ne = (w < 3) ? 13 : 12;           // 3*13+12 = 51
    const bool al = (jj < ne);
    const int  j  = 13 * w + jj;
    const int  gs = al ? (q * 51 + j) : 0;
    // OUT mapping (grp 2): lane lt owns col lt; lanes 0..25 also own col 256+lt
    const int  col0 = lt;
    const bool has2 = (lt < 26);
    const int  col1 = has2 ? (256 + lt) : 0;

    float wA[51], wB[51];              // shared across groups -> one VGPR budget
    float bx = 0.f, by = 0.f;
    float c = 0.f;
    float ep_cur = 0.f;

    __syncthreads();                   // toks + zeroed h buffers visible

    if (grp == 0) {
        #pragma unroll
        for (int k = 0; k < 51; k++) { wA[k] = w_hh1[gs * 51 + k]; wB[k] = 0.f; }
        ep_cur = eproj[toks[0] * G4 + gs];
    } else if (grp == 1) {
        #pragma unroll
        for (int k = 0; k < 51; k++) { wA[k] = w_ih2[gs * 51 + k]; wB[k] = w_hh2[gs * 51 + k]; }
        bx = b2[gs];
    } else {
        #pragma unroll
        for (int k = 0; k < 51; k++) { wA[k] = w_lin[col0 * 51 + k]; wB[k] = w_lin[col1 * 51 + k]; }
        bx = b_lin[col0]; by = b_lin[col1];
    }

    const size_t obase = (size_t)b * TT;

    for (int s = 0; s <= TT + 1; ++s) {
        if (grp == 0) {
            if (s < TT) {
                const int sn = (s + 1 < TT) ? (s + 1) : 0;
                const float ep_nxt = eproj[toks[sn] * G4 + gs];   // prefetch, stays in flight
                const float4* hp = (const float4*)h1b[(s + 1) & 1];   // h1(s-1)
                float a0 = 0.f, a1 = 0.f, a2 = 0.f, a3 = 0.f;
                #pragma unroll
                for (int i = 0; i < 13; i++) {
                    float4 hv = hp[i];
                    const int k = 4 * i;
                    a0 += wA[k] * hv.x;
                    if (k + 1 < 51) a1 += wA[k + 1] * hv.y;
                    if (k + 2 < 51) a2 += wA[k + 2] * hv.z;
                    if (k + 3 < 51) a3 += wA[k + 3] * hv.w;
                }
                const float x = (a0 + a1) + (a2 + a3) + ep_cur;
                const float hn = lstm_act(x, q, c);
                if (q == 0 && al) h1b[s & 1][j] = hn;
                ep_cur = ep_nxt;
            }
        } else if (grp == 1) {
            if (s >= 1 && s <= TT) {
                const float4* hp1 = (const float4*)h1b[(s - 1) & 1];  // h1(t)
                const float4* hp2 = (const float4*)h2b[s & 1];        // h2(t-1)
                float a0 = 0.f, a1 = 0.f, a2 = 0.f, a3 = 0.f;
                #pragma unroll
                for (int i = 0; i < 13; i++) {
                    float4 ha = hp1[i];
                    float4 hb = hp2[i];
                    const int k = 4 * i;
                    a0 += wA[k] * ha.x;       a2 += wB[k] * hb.x;
                    if (k + 1 < 51) { a1 += wA[k + 1] * ha.y; a3 += wB[k + 1] * hb.y; }
                    if (k + 2 < 51) { a0 += wA[k + 2] * ha.z; a2 += wB[k + 2] * hb.z; }
                    if (k + 3 < 51) { a1 += wA[k + 3] * ha.w; a3 += wB[k + 3] * hb.w; }
                }
                const float x = (a0 + a1) + (a2 + a3) + bx;
                const float hn = lstm_act(x, q, c);
                if (q == 0 && al) h2b[(s - 1) & 1][j] = hn;
            }
        } else {
            if (s >= 2) {
                const int u = s - 2;
                const float4* hp = (const float4*)h2b[s & 1];         // h2(u)
                float a0 = 0.f, a1 = 0.f, b0 = 0.f, b1v = 0.f;
                #pragma unroll
                for (int i = 0; i < 13; i++) {
                    float4 hv = hp[i];
                    const int k = 4 * i;
                    a0 += wA[k] * hv.x;       b0  += wB[k] * hv.x;
                    if (k + 1 < 51) { a1 += wA[k + 1] * hv.y; b1v += wB[k + 1] * hv.y; }
                    if (k + 2 < 51) { a0 += wA[k + 2] * hv.z; b0  += wB[k + 2] * hv.z; }
                    if (k + 3 < 51) { a1 += wA[k + 3] * hv.w; b1v += wB[k + 3] * hv.w; }
                }
                out[(obase + u) * VOCAB + col0] = a0 + a1 + bx;       // coalesced per wave
                if (has2)
                    out[(obase + u) * VOCAB + col1] = b0 + b1v + by;
            }
        }
        BAR();
    }
}

extern "C" void kernel_launch(void* const* d_in, const int* in_sizes, int n_in,
                              void* d_out, int out_size, void* d_ws, size_t ws_size,
                              hipStream_t stream) {
    const int*   input = (const int*)  d_in[0];
    const float* embed = (const float*)d_in[2];
    const float* w_ih1 = (const float*)d_in[3];
    const float* w_hh1 = (const float*)d_in[4];
    const float* b1    = (const float*)d_in[5];
    const float* w_ih2 = (const float*)d_in[6];
    const float* w_hh2 = (const float*)d_in[7];
    const float* b2    = (const float*)d_in[8];
    const float* w_lin = (const float*)d_in[9];
    const float* b_lin = (const float*)d_in[10];
    float* out   = (float*)d_out;
    float* eproj = (float*)d_ws;     // 282*204*4 = 230 KB scratch

    const int n1 = VOCAB * G4;
    eproj_kernel<<<(n1 + 255) / 256, 256, 0, stream>>>(embed, w_ih1, b1, eproj);
    lstm_fused_kernel<<<BB, 768, 0, stream>>>(input, eproj, w_hh1, w_ih2, w_hh2, b2,
                                              w_lin, b_lin, out);
}

// Round 9
// 6834.284 us; speedup vs baseline: 1.6505x; 1.6096x over previous
//
#include <hip/hip_runtime.h>

#define HID    51
#define G4     204    // 4*HID
#define EMB    7
#define VOCAB  282
#define TT     1024
#define BB     256

__device__ __forceinline__ float tanh_fast(float x) {
    return 1.0f - 2.0f / (__expf(2.0f * x) + 1.0f);
}

// LDS-only barrier: wait ds ops, do NOT drain vmcnt (keeps eproj prefetch and
// output stores in flight across steps).
#define BAR() asm volatile("s_waitcnt lgkmcnt(0)\n\ts_barrier" ::: "memory")
#define SFENCE() __builtin_amdgcn_sched_barrier(0)

// quad-lane activation + gate gather + cell update (lanes q=0..3 hold i,f,g,o).
// MUTATES c -> must only be called on REAL pipeline steps (R7/R8 bug: calling
// it on the s=0 fill step polluted L2's cell state -> deterministic 2.8e-2 err).
__device__ __forceinline__ float lstm_act(float x, int q, float& c) {
    const float As = (q == 2) ? 2.f : 1.f;
    const float Bs = (q == 2) ? -1.f : 0.f;
    const float act = As / (1.f + __expf(-As * x)) + Bs;  // sigmoid or tanh
    const float v1 = __shfl_xor(act, 1);
    const float v2 = __shfl_xor(act, 2);
    const float v3 = __shfl_xor(v2, 1);
    const float t0 = (q & 1) ? v1 : act, t1 = (q & 1) ? act : v1;
    const float t2 = (q & 1) ? v3 : v2,  t3 = (q & 1) ? v2 : v3;
    const float I = (q & 2) ? t2 : t0, F = (q & 2) ? t3 : t1;
    const float G = (q & 2) ? t0 : t2, O = (q & 2) ? t1 : t3;
    const float cn = F * c + I * G;
    c = cn;
    return O * tanh_fast(cn);
}

// ---------- Kernel A: eproj[v][j] = b1[j] + sum_e embed[v][e]*w_ih1[j][e] ----------
__global__ void eproj_kernel(const float* __restrict__ embed,
                             const float* __restrict__ w_ih1,
                             const float* __restrict__ b1,
                             float* __restrict__ eproj) {
    int idx = blockIdx.x * blockDim.x + threadIdx.x;
    if (idx >= VOCAB * G4) return;
    int v = idx / G4;
    int j = idx - v * G4;
    float acc = b1[j];
    #pragma unroll
    for (int e = 0; e < EMB; e++)
        acc += embed[v * EMB + e] * w_ih1[j * EMB + e];
    eproj[idx] = acc;
}

// ---------- Kernel B: fused recurrent LSTM + output projection -------------------
// 768 threads, 12 waves, 3 groups of 4 waves:
//   G0 (waves 0-3):  L1  h1(s)     - regs: 51 f32 w_hh1 row
//   G1 (waves 4-7):  L2  h2(s-1)   - regs: 51 f32 w_ih2 row; w_hh2 from LDS
//                    + 26 extra OUT cols (256..281) on wave-3 idle lanes (w_lin regs)
//   G2 (waves 8-11): OUT logits(s-2) cols 0..255 -> d_out
//
// REGISTER DISCIPLINE (R3-R7): allocator's VGPR target for flat-wgs=768 is 84,
// immovable in-source. Every lane holds exactly ONE 51-float array (one virtual
// array shared across the mutually exclusive group branches), all f32.
// PIPELINE-FILL DISCIPLINE (R7/R8): all stateful compute fully guarded by
// wave-uniform s-conditions; lstm_act never runs on fill/drain steps.
#define TOKS_PAD 12288   // 48 KB -> total LDS ~90 KB: exactly 1 block/CU fits

__launch_bounds__(768)
__global__ void lstm_fused_kernel(const int* __restrict__ input,
                                  const float* __restrict__ eproj,
                                  const float* __restrict__ w_hh1,
                                  const float* __restrict__ w_ih2,
                                  const float* __restrict__ w_hh2,
                                  const float* __restrict__ b2,
                                  const float* __restrict__ w_lin,
                                  const float* __restrict__ b_lin,
                                  float* __restrict__ out) {
    __shared__ __align__(16) float h1b[2][52];     // f32 h1, 13 float4 rows
    __shared__ __align__(16) float h2b[2][52];     // f32 h2
    __shared__ float shh2[51 * G4];                // w_hh2 TRANSPOSED: [k][gate]
    __shared__ int toks[TOKS_PAD];                 // [0..TT) used; rest = occupancy pad

    const int tid = threadIdx.x;
    const int b   = blockIdx.x;

    for (int i = tid; i < TT; i += 768) toks[i] = input[b * TT + i];
    // stage w_hh2 transposed (one-time, coalesced read)
    for (int i = tid; i < 51 * G4; i += 768) {
        const int g = i / 51, k = i - g * 51;
        shh2[k * G4 + g] = w_hh2[i];
    }
    if (tid < 52) {
        h1b[0][tid] = 0.f; h1b[1][tid] = 0.f;
        h2b[0][tid] = 0.f; h2b[1][tid] = 0.f;
    }

    const int grp = tid >> 8;          // 0=L1, 1=L2, 2=OUT
    const int lt  = tid & 255;
    const int w   = lt >> 6;           // wave-in-group
    const int l   = lt & 63;
    const int jj  = l >> 2;            // 0..15
    const int q   = l & 3;             // gate: 0=i 1=f 2=g 3=o
    const int ne  = (w < 3) ? 16 : 3;  // elems per wave: 16+16+16+3 = 51
    const bool al = (jj < ne);
    const int  j  = 16 * w + jj;       // hidden elem (valid when al)
    const int  gs = al ? (q * 51 + j) : 0;
    const int  col0 = lt;              // G2 output column
    const bool isx  = (grp == 1) && (w == 3) && (jj >= 3) && (q < 2);
    const int  xcol = 256 + (jj - 3) * 2 + q;   // G1 extra output column

    float wU[51];                      // ONE register array shared by all groups
    float bx = 0.f;
    float c = 0.f, ep_cur = 0.f;

    __syncthreads();                   // toks + shh2 + zeroed buffers visible

    if (grp == 0) {
        #pragma unroll
        for (int k = 0; k < 51; k++) wU[k] = w_hh1[gs * 51 + k];
        ep_cur = eproj[toks[0] * G4 + gs];
    } else if (grp == 1) {
        if (isx) {
            #pragma unroll
            for (int k = 0; k < 51; k++) wU[k] = w_lin[xcol * 51 + k];
            bx = b_lin[xcol];
        } else {
            #pragma unroll
            for (int k = 0; k < 51; k++) wU[k] = w_ih2[gs * 51 + k];
            bx = b2[gs];
        }
    } else {
        #pragma unroll
        for (int k = 0; k < 51; k++) wU[k] = w_lin[col0 * 51 + k];
        bx = b_lin[col0];
    }

    const size_t obase = (size_t)b * TT;

    for (int s = 0; s <= TT + 1; ++s) {
        if (grp == 0) {
            // ---- L1: h1(s) = act(eproj(tok_s) + W_hh1 h1(s-1)) ----
            if (s < TT) {
                const int sn = (s + 1 < TT) ? (s + 1) : 0;
                const float ep_nxt = eproj[toks[sn] * G4 + gs];   // prefetch (in flight)
                const float4* hp = (const float4*)h1b[(s + 1) & 1];
                float a0 = 0.f, a1 = 0.f;
                #pragma unroll
                for (int i = 0; i < 13; i++) {
                    float4 hv = hp[i];
                    const int k = 4 * i;
                    a0 += wU[k] * hv.x;
                    if (k + 1 < 51) a1 += wU[k + 1] * hv.y;
                    if (k + 2 < 51) a0 += wU[k + 2] * hv.z;
                    if (k + 3 < 51) a1 += wU[k + 3] * hv.w;
                    if ((i & 3) == 3) SFENCE();
                }
                const float x  = a0 + a1 + ep_cur;
                const float hn = lstm_act(x, q, c);
                if (q == 0 && al) h1b[s & 1][j] = hn;
                ep_cur = ep_nxt;
            }
        } else if (grp == 1) {
            if (!isx) {
                // ---- L2: h2(s-1) = act(W_ih2 h1(s-1) + W_hh2 h2(s-2) + b2) ----
                if (s >= 1 && s <= TT) {
                    const float4* hp1 = (const float4*)h1b[(s - 1) & 1];  // h1(s-1)
                    const float4* hp2 = (const float4*)h2b[s & 1];        // h2(s-2)
                    float a0 = 0.f, a1 = 0.f;
                    #pragma unroll
                    for (int i = 0; i < 13; i++) {            // reg dot: W_ih2 . h1
                        float4 hv = hp1[i];
                        const int k = 4 * i;
                        a0 += wU[k] * hv.x;
                        if (k + 1 < 51) a1 += wU[k + 1] * hv.y;
                        if (k + 2 < 51) a0 += wU[k + 2] * hv.z;
                        if (k + 3 < 51) a1 += wU[k + 3] * hv.w;
                        if ((i & 3) == 3) SFENCE();
                    }
                    float a2 = 0.f, a3 = 0.f;
                    #pragma unroll
                    for (int i = 0; i < 13; i++) {            // LDS dot: W_hh2 . h2
                        float4 hv = hp2[i];
                        const int k = 4 * i;
                        a2 += shh2[k * G4 + gs] * hv.x;
                        if (k + 1 < 51) a3 += shh2[(k + 1) * G4 + gs] * hv.y;
                        if (k + 2 < 51) a2 += shh2[(k + 2) * G4 + gs] * hv.z;
                        if (k + 3 < 51) a3 += shh2[(k + 3) * G4 + gs] * hv.w;
                        if ((i & 3) == 3) SFENCE();
                    }
                    const float x  = (a0 + a1) + (a2 + a3) + bx;
                    const float hn = lstm_act(x, q, c);
                    if (q == 0 && al) h2b[(s - 1) & 1][j] = hn;
                }
            } else {
                // ---- extra OUT cols 256..281: logits(s-2) ----
                if (s >= 2) {
                    const float4* hp = (const float4*)h2b[s & 1];
                    float a0 = 0.f, a1 = 0.f;
                    #pragma unroll
                    for (int i = 0; i < 13; i++) {
                        float4 hv = hp[i];
                        const int k = 4 * i;
                        a0 += wU[k] * hv.x;
                        if (k + 1 < 51) a1 += wU[k + 1] * hv.y;
                        if (k + 2 < 51) a0 += wU[k + 2] * hv.z;
                        if (k + 3 < 51) a1 += wU[k + 3] * hv.w;
                        if ((i & 3) == 3) SFENCE();
                    }
                    out[(obase + (s - 2)) * VOCAB + xcol] = a0 + a1 + bx;
                }
            }
        } else {
            // ---- OUT cols 0..255: logits(s-2) ----
            if (s >= 2) {
                const float4* hp = (const float4*)h2b[s & 1];
                float a0 = 0.f, a1 = 0.f;
                #pragma unroll
                for (int i = 0; i < 13; i++) {
                    float4 hv = hp[i];
                    const int k = 4 * i;
                    a0 += wU[k] * hv.x;
                    if (k + 1 < 51) a1 += wU[k + 1] * hv.y;
                    if (k + 2 < 51) a0 += wU[k + 2] * hv.z;
                    if (k + 3 < 51) a1 += wU[k + 3] * hv.w;
                    if ((i & 3) == 3) SFENCE();
                }
                out[(obase + (s - 2)) * VOCAB + col0] = a0 + a1 + bx;   // coalesced
            }
        }
        BAR();
    }
}

extern "C" void kernel_launch(void* const* d_in, const int* in_sizes, int n_in,
                              void* d_out, int out_size, void* d_ws, size_t ws_size,
                              hipStream_t stream) {
    const int*   input = (const int*)  d_in[0];
    const float* embed = (const float*)d_in[2];
    const float* w_ih1 = (const float*)d_in[3];
    const float* w_hh1 = (const float*)d_in[4];
    const float* b1    = (const float*)d_in[5];
    const float* w_ih2 = (const float*)d_in[6];
    const float* w_hh2 = (const float*)d_in[7];
    const float* b2    = (const float*)d_in[8];
    const float* w_lin = (const float*)d_in[9];
    const float* b_lin = (const float*)d_in[10];
    float* out   = (float*)d_out;
    float* eproj = (float*)d_ws;     // 282*204*4 = 230 KB scratch

    const int n1 = VOCAB * G4;
    eproj_kernel<<<(n1 + 255) / 256, 256, 0, stream>>>(embed, w_ih1, b1, eproj);
    lstm_fused_kernel<<<BB, 768, 0, stream>>>(input, eproj, w_hh1, w_ih2, w_hh2, b2,
                                              w_lin, b_lin, out);
}

// Round 10
// 4244.569 us; speedup vs baseline: 2.6575x; 1.6101x over previous
//
#include <hip/hip_runtime.h>

#define HID    51
#define G4     204    // 4*HID
#define EMB    7
#define VOCAB  282
#define TT     1024
#define BB     256

// LDS-only barrier: wait ds ops, do NOT drain vmcnt (keeps eproj prefetch and
// output stores in flight across steps).
#define BAR() asm volatile("s_waitcnt lgkmcnt(0)\n\ts_barrier" ::: "memory")

__device__ __forceinline__ float tanh_fast(float x) {
    return 1.0f - 2.0f / (__expf(2.0f * x) + 1.0f);
}

// quad-lane activation + gate gather + cell update (lanes q=0..3 hold i,f,g,o).
// MUTATES c -> only call on real pipeline steps (R7/R8 lesson).
__device__ __forceinline__ float lstm_act(float x, int q, float& c) {
    const float As = (q == 2) ? 2.f : 1.f;
    const float Bs = (q == 2) ? -1.f : 0.f;
    const float act = As / (1.f + __expf(-As * x)) + Bs;  // sigmoid or tanh
    const float v1 = __shfl_xor(act, 1);
    const float v2 = __shfl_xor(act, 2);
    const float v3 = __shfl_xor(v2, 1);
    const float t0 = (q & 1) ? v1 : act, t1 = (q & 1) ? act : v1;
    const float t2 = (q & 1) ? v3 : v2,  t3 = (q & 1) ? v2 : v3;
    const float I = (q & 2) ? t2 : t0, F = (q & 2) ? t3 : t1;
    const float G = (q & 2) ? t0 : t2, O = (q & 2) ? t1 : t3;
    const float cn = F * c + I * G;
    c = cn;
    return O * tanh_fast(cn);
}

// load this lane's k-quarter (q) of 4 gate rows from row-major M[204][51]
__device__ __forceinline__ void load_wq(const float* __restrict__ M, int j, int q,
                                        float (&wv)[4][13]) {
    #pragma unroll
    for (int g = 0; g < 4; ++g) {
        #pragma unroll
        for (int kk = 0; kk < 13; ++kk) {
            const int k = 13 * q + kk;
            wv[g][kk] = (k < 51) ? M[(g * 51 + j) * 51 + k] : 0.f;
        }
    }
}

// partial dots of 4 gates over this lane's k-quarter; h is quarter-major hq[4][16]
__device__ __forceinline__ void qdot(const float* __restrict__ h, int q,
                                     const float (&wv)[4][13], float (&p)[4]) {
    const float4* hp = (const float4*)(h + (q << 4));
    const float4 a = hp[0], b = hp[1], d = hp[2];
    const float  e = h[(q << 4) + 12];
    #pragma unroll
    for (int g = 0; g < 4; ++g) {
        p[g] += wv[g][0] * a.x + wv[g][1] * a.y + wv[g][2] * a.z + wv[g][3] * a.w
              + wv[g][4] * b.x + wv[g][5] * b.y + wv[g][6] * b.z + wv[g][7] * b.w
              + wv[g][8] * d.x + wv[g][9] * d.y + wv[g][10] * d.z + wv[g][11] * d.w
              + wv[g][12] * e;
    }
}

// quad all-reduce of the 4 partials; lane q returns gate q's full pre-activation
__device__ __forceinline__ float quad_gate(const float (&p)[4], int q) {
    float t0 = p[0]; t0 += __shfl_xor(t0, 1); t0 += __shfl_xor(t0, 2);
    float t1 = p[1]; t1 += __shfl_xor(t1, 1); t1 += __shfl_xor(t1, 2);
    float t2 = p[2]; t2 += __shfl_xor(t2, 1); t2 += __shfl_xor(t2, 2);
    float t3 = p[3]; t3 += __shfl_xor(t3, 1); t3 += __shfl_xor(t3, 2);
    return (q == 0) ? t0 : (q == 1) ? t1 : (q == 2) ? t2 : t3;
}

// ---------- Kernel A: eproj[v][j] = b1[j] + sum_e embed[v][e]*w_ih1[j][e] ----------
__global__ void eproj_kernel(const float* __restrict__ embed,
                             const float* __restrict__ w_ih1,
                             const float* __restrict__ b1,
                             float* __restrict__ eproj) {
    int idx = blockIdx.x * blockDim.x + threadIdx.x;
    if (idx >= VOCAB * G4) return;
    int v = idx / G4;
    int j = idx - v * G4;
    float acc = b1[j];
    #pragma unroll
    for (int e = 0; e < EMB; e++)
        acc += embed[v * EMB + e] * w_ih1[j * EMB + e];
    eproj[idx] = acc;
}

// ---------- Kernel B: recurrence only (writes h2 into out cols 0..50) ------------
// 768 threads, 12 waves, 3 groups of 4 waves; 2 barriers per step.
//   G0: h1(s) = act(eproj + W_hh1 h1(s-1))          [phase A; eproj prefetch in B]
//   G1: P1 = W_ih2 h1(s-1) -> LDS                   [phase A]
//   G2: P2 = W_hh2 h2(s-2) -> LDS                   [phase A]
//       h2(s-1) = act(P1+P2+b2) -> LDS + out row    [phase B]
// Lane (j, q): q = k-QUARTER for the dot (quad-k-split, 4 LDS reads/lane instead
// of 13), then quad all-reduce hands lane q gate q's pre-activation.
// Every lane holds wv[4][13] = 52 weight regs; live ~70 < the immovable 84
// target for wgs=768 (R3-R9) -> no spill by construction.
__launch_bounds__(768)
__global__ void lstm_rec_kernel(const int* __restrict__ input,
                                const float* __restrict__ eproj,
                                const float* __restrict__ w_hh1,
                                const float* __restrict__ w_ih2,
                                const float* __restrict__ w_hh2,
                                const float* __restrict__ b2,
                                float* __restrict__ out) {
    __shared__ __align__(16) float hq1[2][64];   // h1, quarter-major hq[4][16], padded 0
    __shared__ __align__(16) float hq2[2][64];   // h2, same layout
    __shared__ float P1[G4];
    __shared__ float P2[G4];
    __shared__ int toks[TT];

    const int tid = threadIdx.x;
    const int b   = blockIdx.x;

    for (int i = tid; i < TT; i += 768) toks[i] = input[b * TT + i];
    if (tid < 64) {
        hq1[0][tid] = 0.f; hq1[1][tid] = 0.f;
        hq2[0][tid] = 0.f; hq2[1][tid] = 0.f;
    }

    const int grp = tid >> 8;          // 0=L1, 1=L2-ih, 2=L2-hh(+act)
    const int lt  = tid & 255;
    const int w   = lt >> 6;
    const int l   = lt & 63;
    const int jj  = l >> 2;            // 0..15
    const int q   = l & 3;             // k-quarter AND output-gate index
    const int ne  = (w < 3) ? 16 : 3;  // 16+16+16+3 = 51 elems
    const bool al = (jj < ne);
    const int  j  = al ? (16 * w + jj) : 0;
    const int  gs = q * 51 + j;                       // gate slot (gate q, elem j)
    const int  hslot = (j / 13) * 16 + (j % 13);      // quarter-major store slot

    float wv[4][13];
    float bx = 0.f, c = 0.f, ep_cur = 0.f;

    __syncthreads();                   // toks + zeroed h buffers visible

    if (grp == 0) {
        load_wq(w_hh1, j, q, wv);
        ep_cur = eproj[toks[0] * G4 + gs];
    } else if (grp == 1) {
        load_wq(w_ih2, j, q, wv);
    } else {
        load_wq(w_hh2, j, q, wv);
        bx = b2[gs];
    }

    const size_t obase = (size_t)b * TT;

    for (int s = 0; s <= TT; ++s) {
        // ================= PHASE A =================
        if (grp == 0) {
            if (s < TT) {
                float p[4] = {0.f, 0.f, 0.f, 0.f};
                qdot(hq1[(s + 1) & 1], q, wv, p);          // h1(s-1)
                const float x  = quad_gate(p, q) + ep_cur;
                const float hn = lstm_act(x, q, c);
                if (q == 0 && al) hq1[s & 1][hslot] = hn;  // h1(s)
            }
        } else if (grp == 1) {
            if (s >= 1) {
                float p[4] = {0.f, 0.f, 0.f, 0.f};
                qdot(hq1[(s + 1) & 1], q, wv, p);          // h1(s-1)
                if (al) P1[gs] = quad_gate(p, q);
                else    (void)quad_gate(p, q);
            }
        } else {
            if (s >= 1) {
                float p[4] = {0.f, 0.f, 0.f, 0.f};
                qdot(hq2[s & 1], q, wv, p);                // h2(s-2)
                if (al) P2[gs] = quad_gate(p, q);
                else    (void)quad_gate(p, q);
            }
        }
        BAR();
        // ================= PHASE B =================
        if (grp == 2) {
            if (s >= 1) {
                const float x  = P1[gs] + P2[gs] + bx;
                const float hn = lstm_act(x, q, c);        // h2(s-1)
                if (q == 0 && al) {
                    hq2[(s - 1) & 1][hslot] = hn;
                    out[(obase + (s - 1)) * VOCAB + j] = hn;   // h2 -> cols 0..50
                }
            }
        } else if (grp == 0) {
            if (s + 1 < TT)
                ep_cur = eproj[toks[s + 1] * G4 + gs];     // prefetch, off crit path
        }
        BAR();
    }
}

// ---------- Kernel C: logits in-place: out[row][:] = w_lin @ h + b_lin -----------
// 320 threads (measured VGPR target 128 -> 51 w-regs fit), col-per-thread,
// 64 rows/block in 8-row batches; one __syncthreads between reading a batch's h
// (cols 0..50) and overwriting the batch's rows. Rows are 8B-aligned -> float2.
#define LB 320

__launch_bounds__(LB)
__global__ void logits_kernel(const float* __restrict__ w_lin,
                              const float* __restrict__ b_lin,
                              float* __restrict__ out) {
    const int tid = threadIdx.x;
    const size_t r0 = (size_t)blockIdx.x * 64;
    const bool act = tid < VOCAB;
    const int  cc  = act ? tid : 0;

    float wr[51];
    #pragma unroll
    for (int k = 0; k < 51; ++k) wr[k] = w_lin[cc * 51 + k];
    const float bv = b_lin[cc];

    for (int batch = 0; batch < 8; ++batch) {
        float accs[8];
        #pragma unroll
        for (int r = 0; r < 8; ++r) {
            const float* hrow = out + (r0 + batch * 8 + r) * VOCAB;
            const float2* hp = (const float2*)hrow;        // rows 8B-aligned
            float a0 = bv, a1 = 0.f;
            #pragma unroll
            for (int i = 0; i < 25; ++i) {
                const float2 hv = hp[i];
                a0 += wr[2 * i] * hv.x;
                a1 += wr[2 * i + 1] * hv.y;
            }
            a0 += wr[50] * hrow[50];
            accs[r] = a0 + a1;
        }
        __syncthreads();   // all h reads of this batch complete block-wide
        #pragma unroll
        for (int r = 0; r < 8; ++r)
            if (act) out[(r0 + batch * 8 + r) * VOCAB + cc] = accs[r];
    }
}

extern "C" void kernel_launch(void* const* d_in, const int* in_sizes, int n_in,
                              void* d_out, int out_size, void* d_ws, size_t ws_size,
                              hipStream_t stream) {
    const int*   input = (const int*)  d_in[0];
    const float* embed = (const float*)d_in[2];
    const float* w_ih1 = (const float*)d_in[3];
    const float* w_hh1 = (const float*)d_in[4];
    const float* b1    = (const float*)d_in[5];
    const float* w_ih2 = (const float*)d_in[6];
    const float* w_hh2 = (const float*)d_in[7];
    const float* b2    = (const float*)d_in[8];
    const float* w_lin = (const float*)d_in[9];
    const float* b_lin = (const float*)d_in[10];
    float* out   = (float*)d_out;
    float* eproj = (float*)d_ws;     // 282*204*4 = 230 KB scratch

    const int n1 = VOCAB * G4;
    eproj_kernel<<<(n1 + 255) / 256, 256, 0, stream>>>(embed, w_ih1, b1, eproj);
    lstm_rec_kernel<<<BB, 768, 0, stream>>>(input, eproj, w_hh1, w_ih2, w_hh2, b2, out);
    logits_kernel<<<(BB * TT) / 64, LB, 0, stream>>>(w_lin, b_lin, out);
}